// Round 2
// baseline (9517.892 us; speedup 1.0000x reference)
//
#include <hip/hip_runtime.h>

// B=64, S=512, I=256, O=256 fp32 LSTM.
// out = [h_seq (64*512*256)] [hT (64*256)] [cT (64*256)]
//
// Phase A: xg = x @ Wx^T + bx + bh  (fp32 LDS-tiled GEMM, unchanged)
// Phase B: 256 blocks (one per CU). Block (b,j) owns outputs [64j,64j+64) of
//   batch b: 256 gate rows, local c/h state. Per thread: half a gate row
//   (64 fp16 dot2, weights in 64 arch VGPRs). Per step the 4 blocks of a
//   batch exchange their 64-half h chunks through device-global slots,
//   double-buffered by step parity, synchronized by release-stores +
//   relaxed-poll + acquire-fence. Partners {b,b+64,b+128,b+192} are
//   congruent mod 8 -> same XCD -> L2-local flags (correct at any scope).

#define SS 512

typedef _Float16 h2 __attribute__((ext_vector_type(2)));

__device__ __forceinline__ h2 bch(unsigned u) { return __builtin_bit_cast(h2, u); }

__device__ __forceinline__ unsigned rl(unsigned v, int lane) {
  return (unsigned)__builtin_amdgcn_readlane((int)v, lane);
}

#if __has_builtin(__builtin_amdgcn_fdot2)
__device__ __forceinline__ float dot2f(h2 a, h2 b, float c) {
  return __builtin_amdgcn_fdot2(a, b, c, false);
}
#else
__device__ __forceinline__ float dot2f(h2 a, h2 b, float c) {
  return c + (float)a[0] * (float)b[0] + (float)a[1] * (float)b[1];
}
#endif

__device__ __forceinline__ float sigm(float x) { return 1.f / (1.f + __expf(-x)); }
__device__ __forceinline__ float tanh_f(float x) {
  float e = __expf(-2.f * fabsf(x));      // e in (0,1], no overflow
  float r = (1.f - e) / (1.f + e);
  return copysignf(r, x);
}

// exchange state (device globals: no workspace-size assumptions)
__device__ int g_flags[256][16];                       // [b*4+j][pad] - 64B/flag, no false sharing
__device__ __align__(128) unsigned g_hx[64][2][128];   // [b][parity][128 dwords of fp16 h]

__global__ void zero_flags() {
  int t = blockIdx.x * blockDim.x + threadIdx.x;       // 4096 ints
  ((int*)g_flags)[t] = 0;
}

// ---------------------------------------------------------------- Phase A
__global__ __launch_bounds__(256) void xg_gemm(
    const float* __restrict__ X, const float* __restrict__ W,
    const float* __restrict__ bx, const float* __restrict__ bh,
    float* __restrict__ out)
{
  __shared__ float As[64][68];
  __shared__ float Bs[64][68];
  const int bm = blockIdx.x >> 4;
  const int bn = blockIdx.x & 15;
  const int tid = threadIdx.x;
  const int tn = tid & 15, tm = tid >> 4;
  const int row0 = bm * 64, col0 = bn * 64;
  float acc[4][4] = {};

  for (int k0 = 0; k0 < 256; k0 += 64) {
#pragma unroll
    for (int i = 0; i < 4; i++) {
      const int m = (tid >> 4) + i * 16;
      const int k = (tid & 15) * 4;
      float4 av = *(const float4*)&X[(size_t)(row0 + m) * 256 + k0 + k];
      *(float4*)&As[m][k] = av;
      float4 wv = *(const float4*)&W[(size_t)(col0 + m) * 256 + k0 + k];
      Bs[k + 0][m] = wv.x; Bs[k + 1][m] = wv.y;
      Bs[k + 2][m] = wv.z; Bs[k + 3][m] = wv.w;
    }
    __syncthreads();
#pragma unroll 8
    for (int kk = 0; kk < 64; kk++) {
      const float a0 = As[tm * 4 + 0][kk];
      const float a1 = As[tm * 4 + 1][kk];
      const float a2 = As[tm * 4 + 2][kk];
      const float a3 = As[tm * 4 + 3][kk];
      const float4 bv = *(const float4*)&Bs[kk][tn * 4];
      acc[0][0] = fmaf(a0, bv.x, acc[0][0]); acc[0][1] = fmaf(a0, bv.y, acc[0][1]);
      acc[0][2] = fmaf(a0, bv.z, acc[0][2]); acc[0][3] = fmaf(a0, bv.w, acc[0][3]);
      acc[1][0] = fmaf(a1, bv.x, acc[1][0]); acc[1][1] = fmaf(a1, bv.y, acc[1][1]);
      acc[1][2] = fmaf(a1, bv.z, acc[1][2]); acc[1][3] = fmaf(a1, bv.w, acc[1][3]);
      acc[2][0] = fmaf(a2, bv.x, acc[2][0]); acc[2][1] = fmaf(a2, bv.y, acc[2][1]);
      acc[2][2] = fmaf(a2, bv.z, acc[2][2]); acc[2][3] = fmaf(a2, bv.w, acc[2][3]);
      acc[3][0] = fmaf(a3, bv.x, acc[3][0]); acc[3][1] = fmaf(a3, bv.y, acc[3][1]);
      acc[3][2] = fmaf(a3, bv.z, acc[3][2]); acc[3][3] = fmaf(a3, bv.w, acc[3][3]);
    }
    __syncthreads();
  }

  float bias[4];
#pragma unroll
  for (int j = 0; j < 4; j++) {
    const int col = col0 + tn * 4 + j;
    bias[j] = bx[col] + bh[col];
  }
#pragma unroll
  for (int i = 0; i < 4; i++) {
    float4 o4;
    o4.x = acc[i][0] + bias[0]; o4.y = acc[i][1] + bias[1];
    o4.z = acc[i][2] + bias[2]; o4.w = acc[i][3] + bias[3];
    *(float4*)&out[(size_t)(row0 + tm * 4 + i) * 1024 + col0 + tn * 4] = o4;
  }
}

// ---------------------------------------------------------------- Phase B
// Thread t (0..511): khalf = t>>8, gate g = (t>>6)&3, lane = t&63.
// Gate row R = g*256 + j*64 + lane; k-range [khalf*128, khalf*128+128).
// hv: lane l of each wave holds packed-h dword [khalf*64 + l]; distributed
// to all lanes via v_readlane.
__global__ __launch_bounds__(512) void lstm_scan4(
    const float* __restrict__ xg,   // [64][512][1024]
    const float* __restrict__ Wh,   // [1024][256]
    const float* __restrict__ h0,   // [64][256]
    const float* __restrict__ c0,   // [64][256]
    float* __restrict__ out)
{
  __shared__ float yp[512];

  const int t = threadIdx.x;
  const int b = blockIdx.x & 63;
  const int j = blockIdx.x >> 6;
  const int lane = t & 63;
  const int g = (t >> 6) & 3;
  const int kh = t >> 8;
  const int R = g * 256 + j * 64 + lane;

  // ---- weights: half a gate row as 64 fp16 pairs in VGPRs
  h2 w[64];
  const float* wr = Wh + (size_t)R * 256 + kh * 128;
#pragma unroll
  for (int m = 0; m < 64; ++m) {
    float2 a = *(const float2*)&wr[2 * m];
    h2 x; x[0] = (_Float16)a.x; x[1] = (_Float16)a.y; w[m] = x;
  }

  float cr = (t < 64) ? c0[(size_t)b * 256 + j * 64 + t] : 0.f;

  const float* xr = xg + (size_t)b * SS * 1024;
  float* hs = out + (size_t)b * SS * 256;
  const int fbase = b * 4;

  for (int s = 0; s < SS; ++s) {
    // prefetch this step's xg for the owner lanes (hidden under spin+dots)
    float x0 = 0.f, x1 = 0.f, x2 = 0.f, x3 = 0.f;
    if (t < 64) {
      const float* xp = xr + (size_t)s * 1024 + j * 64 + t;
      x0 = xp[0]; x1 = xp[256]; x2 = xp[512]; x3 = xp[768];
    }

    unsigned hv;
    if (s == 0) {
      float2 a = *(const float2*)&h0[(size_t)b * 256 + (kh * 64 + lane) * 2];
      h2 x; x[0] = (_Float16)a.x; x[1] = (_Float16)a.y;
      hv = __builtin_bit_cast(unsigned, x);
    } else {
      // wait for all 4 chunks of h(s-1) (incl. our own -> also orders LDS/slot reuse)
      int f0, f1, f2, f3;
      do {
        f0 = __hip_atomic_load(&g_flags[fbase + 0][0], __ATOMIC_RELAXED, __HIP_MEMORY_SCOPE_AGENT);
        f1 = __hip_atomic_load(&g_flags[fbase + 1][0], __ATOMIC_RELAXED, __HIP_MEMORY_SCOPE_AGENT);
        f2 = __hip_atomic_load(&g_flags[fbase + 2][0], __ATOMIC_RELAXED, __HIP_MEMORY_SCOPE_AGENT);
        f3 = __hip_atomic_load(&g_flags[fbase + 3][0], __ATOMIC_RELAXED, __HIP_MEMORY_SCOPE_AGENT);
      } while ((f0 < s) | (f1 < s) | (f2 < s) | (f3 < s));
      __builtin_amdgcn_fence(__ATOMIC_ACQUIRE, "agent");
      hv = g_hx[b][(s - 1) & 1][kh * 64 + lane];
    }

    // ---- 64 dot2 over this thread's k-half (4 independent chains)
    float a0 = 0.f, a1 = 0.f, a2 = 0.f, a3 = 0.f;
#pragma unroll
    for (int m = 0; m < 64; m += 4) {
      a0 = dot2f(w[m + 0], bch(rl(hv, m + 0)), a0);
      a1 = dot2f(w[m + 1], bch(rl(hv, m + 1)), a1);
      a2 = dot2f(w[m + 2], bch(rl(hv, m + 2)), a2);
      a3 = dot2f(w[m + 3], bch(rl(hv, m + 3)), a3);
    }
    yp[t] = (a0 + a1) + (a2 + a3);
    __syncthreads();            // partials visible to owner wave

    if (t < 64) {               // owner wave (wave 0): combine + state update
      float y0 = yp[0 * 64 + t] + yp[256 + 0 * 64 + t] + x0;
      float y1 = yp[1 * 64 + t] + yp[256 + 1 * 64 + t] + x1;
      float y2 = yp[2 * 64 + t] + yp[256 + 2 * 64 + t] + x2;
      float y3 = yp[3 * 64 + t] + yp[256 + 3 * 64 + t] + x3;
      const float f = sigm(y0);
      const float i = sigm(y1);
      const float gg = tanh_f(y2);
      const float o = sigm(y3);
      cr = cr * f + i * gg;
      const float h = o * tanh_f(cr);
      hs[(size_t)s * 256 + j * 64 + t] = h;
      if (s == SS - 1) {
        out[8388608 + (size_t)b * 256 + j * 64 + t] = h;   // hT
        out[8404992 + (size_t)b * 256 + j * 64 + t] = cr;  // cT
      }
      // pack h chunk to fp16 dwords and publish
      const float ea = __shfl(h, 2 * t);      // valid for t<32 consumers
      const float eb = __shfl(h, 2 * t + 1);
      if (t < 32) {
        h2 hh; hh[0] = (_Float16)ea; hh[1] = (_Float16)eb;
        g_hx[b][s & 1][32 * j + t] = __builtin_bit_cast(unsigned, hh);
      }
      if (t == 0)
        __hip_atomic_store(&g_flags[fbase + j][0], s + 1, __ATOMIC_RELEASE,
                           __HIP_MEMORY_SCOPE_AGENT);
    }
    // no trailing barrier: next-step yp writes & slot reads are gated by the
    // own-chunk flag (set only after the owner wave's yp reads completed).
  }
}

// ---------------------------------------------------------------- launch
extern "C" void kernel_launch(void* const* d_in, const int* in_sizes, int n_in,
                              void* d_out, int out_size, void* d_ws, size_t ws_size,
                              hipStream_t stream) {
  const float* x  = (const float*)d_in[0];
  const float* h0 = (const float*)d_in[1];
  const float* c0 = (const float*)d_in[2];
  const float* Wh = (const float*)d_in[3];
  const float* bh = (const float*)d_in[4];
  const float* Wx = (const float*)d_in[5];
  const float* bx = (const float*)d_in[6];
  float* out = (float*)d_out;

  float* xg = (float*)d_ws;   // 32768*1024 floats = 128 MB

  zero_flags<<<dim3(16), dim3(256), 0, stream>>>();
  xg_gemm<<<dim3(8192), dim3(256), 0, stream>>>(x, Wx, bx, bh, xg);
  lstm_scan4<<<dim3(256), dim3(512), 0, stream>>>(xg, Wh, h0, c0, out);
}

// Round 3
// 1273.732 us; speedup vs baseline: 7.4724x; 7.4724x over previous
//
#include <hip/hip_runtime.h>

// B=64, S=512, I=256, O=256 fp32 LSTM.
// out = [h_seq (64*512*256)] [hT (64*256)] [cT (64*256)]
//
// Phase A: xg = x @ Wx^T + bx + bh  (fp32 LDS-tiled GEMM, unchanged)
// Phase B: one block per batch (64 blocks, 512 threads, 1 block/CU).
//   Lane-parity gate pairing: even tid=2m owns rows (f[m], g[m]); odd tid=2m+1
//   owns (i[m], o[m]) -> gate exchange is one DPP quad-perm swap (no LDS, no
//   extra barrier). Wh fp16: k in [0,192) in VGPRs, k in [192,256) in LDS.
//   h broadcast via one ds_read_b128 + v_readlane (SGPR operands).
//   Inner product: v_pk_fma_f16 chains (8 fp16x2 chains/row, 16-product
//   sub-chains), fp32 combine via fdot2(chain, 1.0h2, acc). This replaces
//   v_dot2_f32_f16 which measures ~quarter-rate on gfx950 (both R0 and R1
//   land at 4600 cyc/step == the quarter-rate model within 2%).
//   h_sh double-buffered by step parity -> ONE barrier per step.

#define SS 512

typedef _Float16 h2 __attribute__((ext_vector_type(2)));

__device__ __forceinline__ h2 bch(unsigned u) { return __builtin_bit_cast(h2, u); }

__device__ __forceinline__ unsigned rl(unsigned v, int lane) {
  return (unsigned)__builtin_amdgcn_readlane((int)v, lane);
}

#if __has_builtin(__builtin_amdgcn_fdot2)
__device__ __forceinline__ float dot2f(h2 a, h2 b, float c) {
  return __builtin_amdgcn_fdot2(a, b, c, false);
}
#else
__device__ __forceinline__ float dot2f(h2 a, h2 b, float c) {
  return c + (float)a[0] * (float)b[0] + (float)a[1] * (float)b[1];
}
#endif

__device__ __forceinline__ h2 pkfma(h2 a, h2 b, h2 c) {
  return __builtin_elementwise_fma(a, b, c);
}

// lane <-> lane^1 swap via DPP quad_perm(1,0,3,2) - pure VALU, no LDS
__device__ __forceinline__ float swap1(float x) {
  int i = __builtin_bit_cast(int, x);
  i = __builtin_amdgcn_update_dpp(0, i, 0xB1, 0xF, 0xF, true);
  return __builtin_bit_cast(float, i);
}

__device__ __forceinline__ float sigm(float x) { return 1.f / (1.f + __expf(-x)); }
__device__ __forceinline__ float tanh_f(float x) {
  float e = __expf(-2.f * fabsf(x));      // e in (0,1], no overflow
  float r = (1.f - e) / (1.f + e);
  return copysignf(r, x);
}

// ---------------------------------------------------------------- Phase A
__global__ __launch_bounds__(256) void xg_gemm(
    const float* __restrict__ X, const float* __restrict__ W,
    const float* __restrict__ bx, const float* __restrict__ bh,
    float* __restrict__ out)
{
  __shared__ float As[64][68];
  __shared__ float Bs[64][68];
  const int bm = blockIdx.x >> 4;
  const int bn = blockIdx.x & 15;
  const int tid = threadIdx.x;
  const int tn = tid & 15, tm = tid >> 4;
  const int row0 = bm * 64, col0 = bn * 64;
  float acc[4][4] = {};

  for (int k0 = 0; k0 < 256; k0 += 64) {
#pragma unroll
    for (int i = 0; i < 4; i++) {
      const int m = (tid >> 4) + i * 16;
      const int k = (tid & 15) * 4;
      float4 av = *(const float4*)&X[(size_t)(row0 + m) * 256 + k0 + k];
      *(float4*)&As[m][k] = av;
      float4 wv = *(const float4*)&W[(size_t)(col0 + m) * 256 + k0 + k];
      Bs[k + 0][m] = wv.x; Bs[k + 1][m] = wv.y;
      Bs[k + 2][m] = wv.z; Bs[k + 3][m] = wv.w;
    }
    __syncthreads();
#pragma unroll 8
    for (int kk = 0; kk < 64; kk++) {
      const float a0 = As[tm * 4 + 0][kk];
      const float a1 = As[tm * 4 + 1][kk];
      const float a2 = As[tm * 4 + 2][kk];
      const float a3 = As[tm * 4 + 3][kk];
      const float4 bv = *(const float4*)&Bs[kk][tn * 4];
      acc[0][0] = fmaf(a0, bv.x, acc[0][0]); acc[0][1] = fmaf(a0, bv.y, acc[0][1]);
      acc[0][2] = fmaf(a0, bv.z, acc[0][2]); acc[0][3] = fmaf(a0, bv.w, acc[0][3]);
      acc[1][0] = fmaf(a1, bv.x, acc[1][0]); acc[1][1] = fmaf(a1, bv.y, acc[1][1]);
      acc[1][2] = fmaf(a1, bv.z, acc[1][2]); acc[1][3] = fmaf(a1, bv.w, acc[1][3]);
      acc[2][0] = fmaf(a2, bv.x, acc[2][0]); acc[2][1] = fmaf(a2, bv.y, acc[2][1]);
      acc[2][2] = fmaf(a2, bv.z, acc[2][2]); acc[2][3] = fmaf(a2, bv.w, acc[2][3]);
      acc[3][0] = fmaf(a3, bv.x, acc[3][0]); acc[3][1] = fmaf(a3, bv.y, acc[3][1]);
      acc[3][2] = fmaf(a3, bv.z, acc[3][2]); acc[3][3] = fmaf(a3, bv.w, acc[3][3]);
    }
    __syncthreads();
  }

  float bias[4];
#pragma unroll
  for (int j = 0; j < 4; j++) {
    const int col = col0 + tn * 4 + j;
    bias[j] = bx[col] + bh[col];
  }
#pragma unroll
  for (int i = 0; i < 4; i++) {
    float4 o4;
    o4.x = acc[i][0] + bias[0]; o4.y = acc[i][1] + bias[1];
    o4.z = acc[i][2] + bias[2]; o4.w = acc[i][3] + bias[3];
    *(float4*)&out[(size_t)(row0 + tm * 4 + i) * 1024 + col0 + tn * 4] = o4;
  }
}

// ---------------------------------------------------------------- Phase B
// tid = 2m (even):  rows f[m] = 0*256+m and g[m] = 2*256+m
// tid = 2m+1 (odd): rows i[m] = 1*256+m and o[m] = 3*256+m
// i.e. row0 = (tid&1)*256 + (tid>>1), row1 = row0 + 512.
__global__ __launch_bounds__(512) void lstm_scan5(
    const float* __restrict__ xg,   // [64][512][1024]
    const float* __restrict__ Wh,   // [1024][256]
    const float* __restrict__ h0,   // [64][256]
    const float* __restrict__ c0,   // [64][256]
    float* __restrict__ out)
{
  // wl layout: [o(2)][chunk(8)][tid(512)][8 halves] -> contiguous 16B per lane
  __shared__ __align__(16) _Float16 wl[2 * 8 * 512 * 8];   // 128 KB
  __shared__ __align__(16) _Float16 h_sh[2][256];          // double buffer

  const int tid = threadIdx.x;
  const int b = blockIdx.x;
  const int m = tid >> 1;
  const int odd = tid & 1;
  const int row0 = odd * 256 + m;          // f[m] or i[m]

  const float* r0 = Wh + (size_t)row0 * 256;
  const float* r1 = Wh + (size_t)(row0 + 512) * 256;

  // ---- persistent register weights: k in [0,192) as 96 half2 per output row
  h2 w0[96], w1[96];
#pragma unroll
  for (int j = 0; j < 96; ++j) {
    float2 a = *(const float2*)&r0[2 * j];
    float2 c = *(const float2*)&r1[2 * j];
    h2 wa; wa[0] = (_Float16)a.x; wa[1] = (_Float16)a.y; w0[j] = wa;
    h2 wc; wc[0] = (_Float16)c.x; wc[1] = (_Float16)c.y; w1[j] = wc;
  }
  // ---- LDS weights: k in [192,256)
#pragma unroll
  for (int c = 0; c < 8; ++c) {
#pragma unroll
    for (int e = 0; e < 8; ++e) {
      wl[((size_t)(c)*512 + tid) * 8 + e]     = (_Float16)r0[192 + c * 8 + e];
      wl[((size_t)(8 + c)*512 + tid) * 8 + e] = (_Float16)r1[192 + c * 8 + e];
    }
  }
  // ---- initial state
  if (tid < 256) h_sh[0][tid] = (_Float16)h0[(size_t)b * 256 + tid];
  float cr = (!odd) ? c0[(size_t)b * 256 + m] : 0.f;
  __syncthreads();

  const float* xr = xg + (size_t)b * SS * 1024;
  float* hs = out + (size_t)b * SS * 256;

  h2 kOne; kOne[0] = (_Float16)1.0f; kOne[1] = (_Float16)1.0f;

  for (int t = 0; t < SS; ++t) {
    const int p = t & 1;
    // xg for this thread's two rows (latency hidden under the dot phase)
    const float xg0 = xr[(size_t)t * 1024 + row0];
    const float xg1 = xr[(size_t)t * 1024 + row0 + 512];

    // ONE distinct-address LDS read of h: lanes 0..31 cover all 256 halves
    const uint4 hv = *(const uint4*)&h_sh[p][(tid & 31) * 8];

    // 8 fp16x2 accumulator chains per row (16 products per fp16 sub-chain)
    h2 pA[8] = {}, pB[8] = {};

    // k in [0,192): weights in VGPRs, h via readlane SGPRs
#pragma unroll
    for (int ln = 0; ln < 24; ++ln) {
      const unsigned hu0 = rl(hv.x, ln);
      const unsigned hu1 = rl(hv.y, ln);
      const unsigned hu2 = rl(hv.z, ln);
      const unsigned hu3 = rl(hv.w, ln);
      const int j = ln * 4;
      pA[(j + 0) & 7] = pkfma(w0[j + 0], bch(hu0), pA[(j + 0) & 7]);
      pB[(j + 0) & 7] = pkfma(w1[j + 0], bch(hu0), pB[(j + 0) & 7]);
      pA[(j + 1) & 7] = pkfma(w0[j + 1], bch(hu1), pA[(j + 1) & 7]);
      pB[(j + 1) & 7] = pkfma(w1[j + 1], bch(hu1), pB[(j + 1) & 7]);
      pA[(j + 2) & 7] = pkfma(w0[j + 2], bch(hu2), pA[(j + 2) & 7]);
      pB[(j + 2) & 7] = pkfma(w1[j + 2], bch(hu2), pB[(j + 2) & 7]);
      pA[(j + 3) & 7] = pkfma(w0[j + 3], bch(hu3), pA[(j + 3) & 7]);
      pB[(j + 3) & 7] = pkfma(w1[j + 3], bch(hu3), pB[(j + 3) & 7]);
    }
    // k in [192,256): weights from LDS, h via readlane SGPRs
#pragma unroll
    for (int c = 0; c < 8; ++c) {
      const uint4 wa = *(const uint4*)&wl[((size_t)(c)*512 + tid) * 8];
      const uint4 wb = *(const uint4*)&wl[((size_t)(8 + c)*512 + tid) * 8];
      const int ln = 24 + c;
      const unsigned hu0 = rl(hv.x, ln);
      const unsigned hu1 = rl(hv.y, ln);
      const unsigned hu2 = rl(hv.z, ln);
      const unsigned hu3 = rl(hv.w, ln);
      const int j = c * 4;   // chain index base (96+4c) & 7 == (4c) & 7
      pA[(j + 0) & 7] = pkfma(bch(wa.x), bch(hu0), pA[(j + 0) & 7]);
      pB[(j + 0) & 7] = pkfma(bch(wb.x), bch(hu0), pB[(j + 0) & 7]);
      pA[(j + 1) & 7] = pkfma(bch(wa.y), bch(hu1), pA[(j + 1) & 7]);
      pB[(j + 1) & 7] = pkfma(bch(wb.y), bch(hu1), pB[(j + 1) & 7]);
      pA[(j + 2) & 7] = pkfma(bch(wa.z), bch(hu2), pA[(j + 2) & 7]);
      pB[(j + 2) & 7] = pkfma(bch(wb.z), bch(hu2), pB[(j + 2) & 7]);
      pA[(j + 3) & 7] = pkfma(bch(wa.w), bch(hu3), pA[(j + 3) & 7]);
      pB[(j + 3) & 7] = pkfma(bch(wb.w), bch(hu3), pB[(j + 3) & 7]);
    }
    // fp32 combine of the 16 fp16 sub-chain totals per row
    float y0 = xg0, y1 = xg1;
#pragma unroll
    for (int c = 0; c < 8; ++c) {
      y0 = dot2f(pA[c], kOne, y0);
      y1 = dot2f(pB[c], kOne, y1);
    }

    // gates: even lane has (f,g); odd lane has (i,o). f,i,o=sigm; g=tanh.
    const float u0 = sigm(y0);                       // f (even) / i (odd)
    const float z  = odd ? y1 : 2.f * y1;
    const float sz = sigm(z);
    const float u1 = odd ? sz : 2.f * sz - 1.f;      // o (odd) / tanh g (even)

    // exchange with partner lane (pure-VALU DPP quad-perm swap)
    const float v0 = swap1(u0);                      // even receives i
    const float v1 = swap1(u1);                      // even receives o

    if (!odd) {
      cr = cr * u0 + v0 * u1;                        // c = c*f + i*g
      const float h = v1 * tanh_f(cr);               // h = o*tanh(c)
      hs[(size_t)t * 256 + m] = h;
      h_sh[p ^ 1][m] = (_Float16)h;
      if (t == SS - 1) {
        out[8388608 + (size_t)b * 256 + m] = h;      // hT
        out[8404992 + (size_t)b * 256 + m] = cr;     // cT
      }
    }
    __syncthreads();            // h_sh[p^1] ready for next step
  }
}

// ---------------------------------------------------------------- launch
extern "C" void kernel_launch(void* const* d_in, const int* in_sizes, int n_in,
                              void* d_out, int out_size, void* d_ws, size_t ws_size,
                              hipStream_t stream) {
  const float* x  = (const float*)d_in[0];
  const float* h0 = (const float*)d_in[1];
  const float* c0 = (const float*)d_in[2];
  const float* Wh = (const float*)d_in[3];
  const float* bh = (const float*)d_in[4];
  const float* Wx = (const float*)d_in[5];
  const float* bx = (const float*)d_in[6];
  float* out = (float*)d_out;

  float* xg = (float*)d_ws;   // 32768*1024 floats = 128 MB

  xg_gemm<<<dim3(8192), dim3(256), 0, stream>>>(x, Wx, bx, bh, xg);
  lstm_scan5<<<dim3(64), dim3(512), 0, stream>>>(xg, Wh, h0, c0, out);
}